// Round 7
// baseline (44.683 us; speedup 1.0000x reference)
//
#include <hip/hip_runtime.h>

// CenterWeightedCIoULoss: mean over N matched pairs. 128 MiB in, 4 B out.
// R6: R5's pipelined partial kernel (at the delivered-BW floor: 5.6 TB/s
// effective, MLP-insensitive across R1/R3/R5) + fire-and-forget pre-scaled
// atomicAdd tail replacing the final kernel (~3.5us -> ~1us memset node).
// R4 proved the plain atomic is harmless (its slowdown was the vmcnt(0)
// drain); R2's failure was the fence+counter chain, not the atomic.

#define EPSF 1e-7f
#define BLOCK 256
#define U 2                       // elems per thread per stage
#define STAGE_ELEMS (BLOCK * U)   // 512 elems per block per stage
#define GRID 2048                 // 8 blocks/CU on 256 CUs

__device__ __forceinline__ float fast_rcp(float x) {
    return __builtin_amdgcn_rcpf(x);
}

__device__ __forceinline__ float ciou_elem(float4 p, float4 t) {
    const float px1 = p.x, py1 = p.y, px2 = p.z, py2 = p.w;
    const float tx1 = t.x, ty1 = t.y, tx2 = t.z, ty2 = t.w;

    float iw = fminf(px2, tx2) - fmaxf(px1, tx1);
    float ih = fminf(py2, ty2) - fmaxf(py1, ty1);
    iw = fmaxf(iw, 0.f);
    ih = fmaxf(ih, 0.f);
    const float inter  = iw * ih;
    const float pw = px2 - px1, ph = py2 - py1;
    const float tw = tx2 - tx1, th = ty2 - ty1;
    const float p_area = pw * ph;
    const float t_area = tw * th;
    const float iou = inter * fast_rcp(p_area + t_area - inter + EPSF);

    const float dcx = 0.5f * ((px1 + px2) - (tx1 + tx2));
    const float dcy = 0.5f * ((py1 + py2) - (ty1 + ty2));
    const float center_dist_sq = dcx * dcx + dcy * dcy;
    const float cw = fmaxf(px2, tx2) - fminf(px1, tx1);
    const float ch = fmaxf(py2, ty2) - fminf(py1, ty1);
    const float c_diag_sq = cw * cw + ch * ch + EPSF;  // eps twice: faithful
    const float center_term = center_dist_sq * fast_rcp(c_diag_sq + EPSF);

    const float sw = (pw - tw) * fast_rcp(tw + EPSF);
    const float sh = (ph - th) * fast_rcp(th + EPSF);
    const float size_term = sw * sw + sh * sh;

    return (1.f - iou) + 2.f * center_term + size_term;
}

// block reduce; result valid in thread 0. Fire-and-forget atomic tail.
__device__ __forceinline__ void block_reduce_atomic(float acc, float scale,
                                                    float* out) {
    #pragma unroll
    for (int off = 32; off > 0; off >>= 1)
        acc += __shfl_down(acc, off, 64);
    __shared__ float lds_ws[BLOCK / 64];
    const int lane = threadIdx.x & 63;
    const int wave = threadIdx.x >> 6;
    if (lane == 0) lds_ws[wave] = acc;
    __syncthreads();
    if (threadIdx.x == 0) {
        float blk = 0.f;
        #pragma unroll
        for (int w = 0; w < BLOCK / 64; ++w) blk += lds_ws[w];
        atomicAdd(out, blk * scale);  // no fence, no counter: block retires now
    }
}

// Pipelined kernel: requires n == GRID * nstages * STAGE_ELEMS, nstages even.
__global__ __launch_bounds__(BLOCK) void ciou_partial_pipe(
        const float4* __restrict__ pred,
        const float4* __restrict__ targ,
        float* __restrict__ out, int nstages, float inv_n) {
    const long long blockBase =
        (long long)blockIdx.x * nstages * STAGE_ELEMS + threadIdx.x;
    const float4* pb = pred + blockBase;
    const float4* tb = targ + blockBase;

    float4 pA[U], tA[U], pB[U], tB[U];

#define LOAD(PX, TX, s)                                   \
    _Pragma("unroll")                                     \
    for (int u = 0; u < U; ++u) {                         \
        PX[u] = pb[(s) * STAGE_ELEMS + u * BLOCK];        \
        TX[u] = tb[(s) * STAGE_ELEMS + u * BLOCK];        \
    }

    float acc0 = 0.f, acc1 = 0.f;
#define COMPUTE(PX, TX)                                   \
    acc0 += ciou_elem(PX[0], TX[0]);                      \
    acc1 += ciou_elem(PX[1], TX[1]);

    LOAD(pA, tA, 0)
    LOAD(pB, tB, 1)

    int s = 2;
    for (; s < nstages; s += 2) {
        COMPUTE(pA, tA)
        LOAD(pA, tA, s)
        COMPUTE(pB, tB)
        LOAD(pB, tB, s + 1)
    }
    COMPUTE(pA, tA)
    COMPUTE(pB, tB)

#undef LOAD
#undef COMPUTE

    block_reduce_atomic(acc0 + acc1, inv_n, out);
}

// Generic fallback: grid-stride, any n.
__global__ __launch_bounds__(BLOCK) void ciou_partial_generic(
        const float4* __restrict__ pred,
        const float4* __restrict__ targ,
        float* __restrict__ out, int n, float inv_n) {
    const int tid = blockIdx.x * BLOCK + threadIdx.x;
    const int stride = GRID * BLOCK;
    float acc = 0.f;
    for (int i = tid; i < n; i += stride)
        acc += ciou_elem(pred[i], targ[i]);
    block_reduce_atomic(acc, inv_n, out);
}

extern "C" void kernel_launch(void* const* d_in, const int* in_sizes, int n_in,
                              void* d_out, int out_size, void* d_ws, size_t ws_size,
                              hipStream_t stream) {
    const float4* pred = (const float4*)d_in[0];
    const float4* targ = (const float4*)d_in[1];
    float* out = (float*)d_out;

    const int n = in_sizes[0] / 4;  // number of boxes (4,194,304)
    const float inv_n = 1.0f / (float)n;
    const long long denom = (long long)GRID * STAGE_ELEMS;
    const int nstages = (int)(n / denom);  // 4 at N=4M

    // out accumulates via atomics -> must start at 0 every call (replays!)
    hipMemsetAsync(d_out, 0, sizeof(float), stream);

    if ((long long)nstages * denom == n && nstages >= 2 && (nstages & 1) == 0) {
        ciou_partial_pipe<<<GRID, BLOCK, 0, stream>>>(pred, targ, out, nstages, inv_n);
    } else {
        ciou_partial_generic<<<GRID, BLOCK, 0, stream>>>(pred, targ, out, n, inv_n);
    }
}

// Round 8
// 29.634 us; speedup vs baseline: 1.5078x; 1.5078x over previous
//
#include <hip/hip_runtime.h>

// CenterWeightedCIoULoss: mean over N matched pairs. 128 MiB in, 4 B out.
// R7: revert R6's atomic tail (2048 same-address RMWs burst-serialized at
// full-residency kernel end: +17us wall, kernel dur unchanged). Keep R5's
// pipelined partial (at the delivered-BW floor ~5.7 TB/s across 3 different
// structures). Final kernel slimmed to ONE wave: 8 float4/lane + shfl
// reduce, no LDS/syncthreads.

#define EPSF 1e-7f
#define BLOCK 256
#define U 2                       // elems per thread per stage
#define STAGE_ELEMS (BLOCK * U)   // 512 elems per block per stage
#define GRID 2048                 // 8 blocks/CU on 256 CUs; full residency

__device__ __forceinline__ float fast_rcp(float x) {
    return __builtin_amdgcn_rcpf(x);
}

__device__ __forceinline__ float ciou_elem(float4 p, float4 t) {
    const float px1 = p.x, py1 = p.y, px2 = p.z, py2 = p.w;
    const float tx1 = t.x, ty1 = t.y, tx2 = t.z, ty2 = t.w;

    float iw = fminf(px2, tx2) - fmaxf(px1, tx1);
    float ih = fminf(py2, ty2) - fmaxf(py1, ty1);
    iw = fmaxf(iw, 0.f);
    ih = fmaxf(ih, 0.f);
    const float inter  = iw * ih;
    const float pw = px2 - px1, ph = py2 - py1;
    const float tw = tx2 - tx1, th = ty2 - ty1;
    const float p_area = pw * ph;
    const float t_area = tw * th;
    const float iou = inter * fast_rcp(p_area + t_area - inter + EPSF);

    const float dcx = 0.5f * ((px1 + px2) - (tx1 + tx2));
    const float dcy = 0.5f * ((py1 + py2) - (ty1 + ty2));
    const float center_dist_sq = dcx * dcx + dcy * dcy;
    const float cw = fmaxf(px2, tx2) - fminf(px1, tx1);
    const float ch = fmaxf(py2, ty2) - fminf(py1, ty1);
    const float c_diag_sq = cw * cw + ch * ch + EPSF;  // eps twice: faithful
    const float center_term = center_dist_sq * fast_rcp(c_diag_sq + EPSF);

    const float sw = (pw - tw) * fast_rcp(tw + EPSF);
    const float sh = (ph - th) * fast_rcp(th + EPSF);
    const float size_term = sw * sw + sh * sh;

    return (1.f - iou) + 2.f * center_term + size_term;
}

__device__ __forceinline__ float wave_block_reduce(float acc, float* lds_ws) {
    #pragma unroll
    for (int off = 32; off > 0; off >>= 1)
        acc += __shfl_down(acc, off, 64);
    const int lane = threadIdx.x & 63;
    const int wave = threadIdx.x >> 6;
    if (lane == 0) lds_ws[wave] = acc;
    __syncthreads();
    float s = 0.f;
    if (threadIdx.x == 0) {
        #pragma unroll
        for (int w = 0; w < BLOCK / 64; ++w) s += lds_ws[w];
    }
    return s;  // valid in thread 0 only
}

// Pipelined kernel: requires n == GRID * nstages * STAGE_ELEMS, nstages even.
__global__ __launch_bounds__(BLOCK) void ciou_partial_pipe(
        const float4* __restrict__ pred,
        const float4* __restrict__ targ,
        float* __restrict__ partial, int nstages) {
    const long long blockBase =
        (long long)blockIdx.x * nstages * STAGE_ELEMS + threadIdx.x;
    const float4* pb = pred + blockBase;
    const float4* tb = targ + blockBase;

    float4 pA[U], tA[U], pB[U], tB[U];

#define LOAD(PX, TX, s)                                   \
    _Pragma("unroll")                                     \
    for (int u = 0; u < U; ++u) {                         \
        PX[u] = pb[(s) * STAGE_ELEMS + u * BLOCK];        \
        TX[u] = tb[(s) * STAGE_ELEMS + u * BLOCK];        \
    }

    float acc0 = 0.f, acc1 = 0.f;
#define COMPUTE(PX, TX)                                   \
    acc0 += ciou_elem(PX[0], TX[0]);                      \
    acc1 += ciou_elem(PX[1], TX[1]);

    LOAD(pA, tA, 0)
    LOAD(pB, tB, 1)

    int s = 2;
    for (; s < nstages; s += 2) {
        COMPUTE(pA, tA)
        LOAD(pA, tA, s)
        COMPUTE(pB, tB)
        LOAD(pB, tB, s + 1)
    }
    COMPUTE(pA, tA)
    COMPUTE(pB, tB)

#undef LOAD
#undef COMPUTE

    float acc = acc0 + acc1;
    __shared__ float lds_ws[BLOCK / 64];
    const float blk = wave_block_reduce(acc, lds_ws);
    if (threadIdx.x == 0) partial[blockIdx.x] = blk;
}

// Generic fallback: grid-stride, any n. Still writes GRID partials.
__global__ __launch_bounds__(BLOCK) void ciou_partial_generic(
        const float4* __restrict__ pred,
        const float4* __restrict__ targ,
        float* __restrict__ partial, int n) {
    const int tid = blockIdx.x * BLOCK + threadIdx.x;
    const int stride = GRID * BLOCK;
    float acc = 0.f;
    for (int i = tid; i < n; i += stride)
        acc += ciou_elem(pred[i], targ[i]);
    __shared__ float lds_ws[BLOCK / 64];
    const float blk = wave_block_reduce(acc, lds_ws);
    if (threadIdx.x == 0) partial[blockIdx.x] = blk;
}

// Single-wave final: GRID partials (multiple of 256), float4 loads, shfl only.
__global__ __launch_bounds__(64) void ciou_final_kernel(
        const float* __restrict__ partial, int nparts,
        float* __restrict__ out, float inv_n) {
    const float4* pv = (const float4*)partial;
    const int nvec = nparts >> 2;  // 512 at GRID=2048
    float acc = 0.f;
    for (int i = threadIdx.x; i < nvec; i += 64) {
        const float4 v = pv[i];
        acc += (v.x + v.y) + (v.z + v.w);
    }
    #pragma unroll
    for (int off = 32; off > 0; off >>= 1)
        acc += __shfl_down(acc, off, 64);
    if (threadIdx.x == 0) out[0] = acc * inv_n;
}

extern "C" void kernel_launch(void* const* d_in, const int* in_sizes, int n_in,
                              void* d_out, int out_size, void* d_ws, size_t ws_size,
                              hipStream_t stream) {
    const float4* pred = (const float4*)d_in[0];
    const float4* targ = (const float4*)d_in[1];
    float* out = (float*)d_out;
    float* partial = (float*)d_ws;

    const int n = in_sizes[0] / 4;  // number of boxes (4,194,304)
    const long long denom = (long long)GRID * STAGE_ELEMS;
    const int nstages = (int)(n / denom);  // 4 at N=4M

    if ((long long)nstages * denom == n && nstages >= 2 && (nstages & 1) == 0) {
        ciou_partial_pipe<<<GRID, BLOCK, 0, stream>>>(pred, targ, partial, nstages);
    } else {
        ciou_partial_generic<<<GRID, BLOCK, 0, stream>>>(pred, targ, partial, n);
    }
    ciou_final_kernel<<<1, 64, 0, stream>>>(partial, GRID, out, 1.0f / (float)n);
}

// Round 9
// 27.520 us; speedup vs baseline: 1.6236x; 1.0768x over previous
//
#include <hip/hip_runtime.h>

// CenterWeightedCIoULoss: mean over N matched pairs. 128 MiB in, 4 B out.
// R8 = R5 verbatim (best measured: 27.5us). Pipelined double-buffer partial
// (delivered-BW floor ~5.7 TB/s, proven MLP/occupancy-insensitive) +
// 256-thread float4 final kernel. R6/R7 established: atomic tails lose
// (same-address RMW burst ~8ns each), final-kernel cost is the launch node
// (~2-3us irreducible), not its execution shape.

#define EPSF 1e-7f
#define BLOCK 256
#define U 2                       // elems per thread per stage
#define STAGE_ELEMS (BLOCK * U)   // 512 elems per block per stage
#define GRID 2048                 // 8 blocks/CU on 256 CUs; full residency

__device__ __forceinline__ float fast_rcp(float x) {
    return __builtin_amdgcn_rcpf(x);
}

__device__ __forceinline__ float ciou_elem(float4 p, float4 t) {
    const float px1 = p.x, py1 = p.y, px2 = p.z, py2 = p.w;
    const float tx1 = t.x, ty1 = t.y, tx2 = t.z, ty2 = t.w;

    float iw = fminf(px2, tx2) - fmaxf(px1, tx1);
    float ih = fminf(py2, ty2) - fmaxf(py1, ty1);
    iw = fmaxf(iw, 0.f);
    ih = fmaxf(ih, 0.f);
    const float inter  = iw * ih;
    const float pw = px2 - px1, ph = py2 - py1;
    const float tw = tx2 - tx1, th = ty2 - ty1;
    const float p_area = pw * ph;
    const float t_area = tw * th;
    const float iou = inter * fast_rcp(p_area + t_area - inter + EPSF);

    const float dcx = 0.5f * ((px1 + px2) - (tx1 + tx2));
    const float dcy = 0.5f * ((py1 + py2) - (ty1 + ty2));
    const float center_dist_sq = dcx * dcx + dcy * dcy;
    const float cw = fmaxf(px2, tx2) - fminf(px1, tx1);
    const float ch = fmaxf(py2, ty2) - fminf(py1, ty1);
    const float c_diag_sq = cw * cw + ch * ch + EPSF;  // eps twice: faithful
    const float center_term = center_dist_sq * fast_rcp(c_diag_sq + EPSF);

    const float sw = (pw - tw) * fast_rcp(tw + EPSF);
    const float sh = (ph - th) * fast_rcp(th + EPSF);
    const float size_term = sw * sw + sh * sh;

    return (1.f - iou) + 2.f * center_term + size_term;
}

__device__ __forceinline__ float wave_block_reduce(float acc, float* lds_ws) {
    #pragma unroll
    for (int off = 32; off > 0; off >>= 1)
        acc += __shfl_down(acc, off, 64);
    const int lane = threadIdx.x & 63;
    const int wave = threadIdx.x >> 6;
    if (lane == 0) lds_ws[wave] = acc;
    __syncthreads();
    float s = 0.f;
    if (threadIdx.x == 0) {
        #pragma unroll
        for (int w = 0; w < BLOCK / 64; ++w) s += lds_ws[w];
    }
    return s;  // valid in thread 0 only
}

// Pipelined kernel: requires n == GRID * nstages * STAGE_ELEMS, nstages even.
__global__ __launch_bounds__(BLOCK) void ciou_partial_pipe(
        const float4* __restrict__ pred,
        const float4* __restrict__ targ,
        float* __restrict__ partial, int nstages) {
    const long long blockBase =
        (long long)blockIdx.x * nstages * STAGE_ELEMS + threadIdx.x;
    const float4* pb = pred + blockBase;
    const float4* tb = targ + blockBase;

    float4 pA[U], tA[U], pB[U], tB[U];

#define LOAD(PX, TX, s)                                   \
    _Pragma("unroll")                                     \
    for (int u = 0; u < U; ++u) {                         \
        PX[u] = pb[(s) * STAGE_ELEMS + u * BLOCK];        \
        TX[u] = tb[(s) * STAGE_ELEMS + u * BLOCK];        \
    }

    float acc0 = 0.f, acc1 = 0.f;
#define COMPUTE(PX, TX)                                   \
    acc0 += ciou_elem(PX[0], TX[0]);                      \
    acc1 += ciou_elem(PX[1], TX[1]);

    LOAD(pA, tA, 0)
    LOAD(pB, tB, 1)

    int s = 2;
    for (; s < nstages; s += 2) {
        COMPUTE(pA, tA)
        LOAD(pA, tA, s)
        COMPUTE(pB, tB)
        LOAD(pB, tB, s + 1)
    }
    COMPUTE(pA, tA)
    COMPUTE(pB, tB)

#undef LOAD
#undef COMPUTE

    float acc = acc0 + acc1;
    __shared__ float lds_ws[BLOCK / 64];
    const float blk = wave_block_reduce(acc, lds_ws);
    if (threadIdx.x == 0) partial[blockIdx.x] = blk;
}

// Generic fallback: grid-stride, any n. Still writes GRID partials.
__global__ __launch_bounds__(BLOCK) void ciou_partial_generic(
        const float4* __restrict__ pred,
        const float4* __restrict__ targ,
        float* __restrict__ partial, int n) {
    const int tid = blockIdx.x * BLOCK + threadIdx.x;
    const int stride = GRID * BLOCK;
    float acc = 0.f;
    for (int i = tid; i < n; i += stride)
        acc += ciou_elem(pred[i], targ[i]);
    __shared__ float lds_ws[BLOCK / 64];
    const float blk = wave_block_reduce(acc, lds_ws);
    if (threadIdx.x == 0) partial[blockIdx.x] = blk;
}

__global__ __launch_bounds__(BLOCK) void ciou_final_kernel(
        const float* __restrict__ partial, int nparts,
        float* __restrict__ out, float inv_n) {
    const float4* pv = (const float4*)partial;  // nparts % 4 == 0
    const int nvec = nparts >> 2;
    float acc = 0.f;
    for (int i = threadIdx.x; i < nvec; i += BLOCK) {
        const float4 v = pv[i];
        acc += (v.x + v.y) + (v.z + v.w);
    }
    __shared__ float lds_ws[BLOCK / 64];
    const float s = wave_block_reduce(acc, lds_ws);
    if (threadIdx.x == 0) out[0] = s * inv_n;
}

extern "C" void kernel_launch(void* const* d_in, const int* in_sizes, int n_in,
                              void* d_out, int out_size, void* d_ws, size_t ws_size,
                              hipStream_t stream) {
    const float4* pred = (const float4*)d_in[0];
    const float4* targ = (const float4*)d_in[1];
    float* out = (float*)d_out;
    float* partial = (float*)d_ws;

    const int n = in_sizes[0] / 4;  // number of boxes (4,194,304)
    const long long denom = (long long)GRID * STAGE_ELEMS;
    const int nstages = (int)(n / denom);  // 4 at N=4M

    if ((long long)nstages * denom == n && nstages >= 2 && (nstages & 1) == 0) {
        ciou_partial_pipe<<<GRID, BLOCK, 0, stream>>>(pred, targ, partial, nstages);
    } else {
        ciou_partial_generic<<<GRID, BLOCK, 0, stream>>>(pred, targ, partial, n);
    }
    ciou_final_kernel<<<1, BLOCK, 0, stream>>>(partial, GRID, out, 1.0f / (float)n);
}